// Round 3
// baseline (35.468 us; speedup 1.0000x reference)
//
#include <hip/hip_runtime.h>
#include <cfloat>

#define NS 7
#define NC 256
#define NH 64
#define NW 64
#define NR 128
#define RG 32            // rois per block
#define LDW 68           // padded LDS row stride: 16B-aligned b128 writes, rows shift banks by 4

// Block = (channel, roi-group of 32). Stage the 16KB channel plane in LDS once,
// precompute bin tables, then thread-per-output window max from LDS.
__global__ __launch_bounds__(256) void roi_pool_kernel(
    const float* __restrict__ f,
    const int* __restrict__ rois,
    float* __restrict__ out)
{
    __shared__ float plane[NH * LDW];                 // 17408 B
    __shared__ int hs[RG][NS], he[RG][NS];            // bin tables
    __shared__ int ws[RG][NS], we[RG][NS];            // total 3584 B

    const int tid = threadIdx.x;
    const int c   = blockIdx.x >> 2;   // channel
    const int g   = blockIdx.x & 3;    // roi group

    // Phase A: stage channel plane into LDS. Coalesced float4 global reads,
    // 16B-aligned LDS writes (row stride 68 floats, 64%4==0 so no row-crossing).
    {
        const float4* src = (const float4*)(f + (size_t)c * (NH * NW));
        #pragma unroll
        for (int k = 0; k < 4; ++k) {
            int q  = tid + k * 256;    // float4 index 0..1023
            int h  = q >> 4;           // 16 float4 per row
            int w4 = q & 15;
            float4 v = src[q];
            *(float4*)&plane[h * LDW + w4 * 4] = v;
        }
    }

    // Phase B: per-roi adaptive-pool bin boundaries (PyTorch semantics).
    if (tid < RG) {
        int r  = g * RG + tid;
        int x1 = rois[4*r+0], y1 = rois[4*r+1];
        int x2 = rois[4*r+2], y2 = rois[4*r+3];
        int Lh = x2 - x1 + 1, Lw = y2 - y1 + 1;
        #pragma unroll
        for (int i = 0; i < NS; ++i) {
            hs[tid][i] = x1 + (i * Lh) / NS;
            he[tid][i] = x1 + ((i + 1) * Lh + NS - 1) / NS;
            ws[tid][i] = y1 + (i * Lw) / NS;
            we[tid][i] = y1 + ((i + 1) * Lw + NS - 1) / NS;
        }
    }

    __syncthreads();

    // Phase C: one thread per output element (32 rois x 49 bins = 1568).
    for (int o = tid; o < RG * NS * NS; o += 256) {
        int lr  = o / (NS * NS);
        int bin = o - lr * (NS * NS);
        int i   = bin / NS;
        int j   = bin - i * NS;

        int h0 = hs[lr][i], h1 = he[lr][i];
        int w0 = ws[lr][j], w1 = we[lr][j];

        float m = -FLT_MAX;
        for (int h = h0; h < h1; ++h) {
            const float* row = &plane[h * LDW];
            for (int w = w0; w < w1; ++w)
                m = fmaxf(m, row[w]);
        }

        int r = g * RG + lr;
        out[((size_t)(r * NC + c)) * (NS * NS) + bin] = m;
    }
}

extern "C" void kernel_launch(void* const* d_in, const int* in_sizes, int n_in,
                              void* d_out, int out_size, void* d_ws, size_t ws_size,
                              hipStream_t stream)
{
    const float* feature_map = (const float*)d_in[0];
    const int*   rois        = (const int*)d_in[1];
    float*       out         = (float*)d_out;

    const int grid  = NC * (NR / RG);  // 256 channels * 4 roi-groups = 1024
    const int block = 256;

    roi_pool_kernel<<<grid, block, 0, stream>>>(feature_map, rois, out);
}

// Round 4
// 23.529 us; speedup vs baseline: 1.5074x; 1.5074x over previous
//
#include <hip/hip_runtime.h>
#include <cfloat>

#define NS 7
#define NC 256
#define NH 64
#define NW 64
#define NR 128
#define RG 16            // rois per block
#define PR 68            // padded plane rows (safe h+3 reads)
#define PW 68            // padded plane row stride (safe w+3 reads)

// Block = (channel, roi-group of 16). Grid = 256*8 = 2048 = 8 blocks/CU,
// all resident. Stage channel plane in LDS; each output reads its window
// in 4x4 batches of independent ds_reads (one latency hop), predicated fmax.
__global__ __launch_bounds__(256, 8) void roi_pool_kernel(
    const float* __restrict__ f,
    const int* __restrict__ rois,
    float* __restrict__ out)
{
    __shared__ float plane[PR][PW];   // 18,496 B

    const int tid = threadIdx.x;
    const int c   = blockIdx.x >> 3;  // channel
    const int g   = blockIdx.x & 7;   // roi group

    // Stage 64x64 plane: 1024 float4s, 4 per thread, independent issues.
    {
        const float4* src = (const float4*)(f + (size_t)c * (NH * NW));
        #pragma unroll
        for (int k = 0; k < 4; ++k) {
            int q  = tid + k * 256;        // float4 index 0..1023
            int h  = q >> 4;               // 16 float4 per 64-wide row
            int w4 = (q & 15) * 4;
            float4 v = src[q];
            *(float4*)&plane[h][w4] = v;
        }
    }

    __syncthreads();

    // Outputs: RG*49 = 784 per block, ~3 per thread.
    for (int o = tid; o < RG * NS * NS; o += 256) {
        int lr  = o / (NS * NS);
        int bin = o - lr * (NS * NS);
        int i   = bin / NS;
        int j   = bin - i * NS;
        int r   = g * RG + lr;

        int x1 = rois[4 * r + 0];   // H range
        int y1 = rois[4 * r + 1];   // W range
        int x2 = rois[4 * r + 2];
        int y2 = rois[4 * r + 3];
        int Lh = x2 - x1 + 1;
        int Lw = y2 - y1 + 1;

        int h0 = x1 + (i * Lh) / NS;
        int h1 = x1 + ((i + 1) * Lh + NS - 1) / NS;
        int w0 = y1 + (j * Lw) / NS;
        int w1 = y1 + ((j + 1) * Lw + NS - 1) / NS;

        float m = -FLT_MAX;
        for (int h = h0; h < h1; h += 4) {
            for (int w = w0; w < w1; w += 4) {
                // 16 unconditional independent LDS reads (pad makes them safe),
                // then predicated max. One waitcnt for the whole tile.
                float v[16];
                #pragma unroll
                for (int dh = 0; dh < 4; ++dh)
                    #pragma unroll
                    for (int dw = 0; dw < 4; ++dw)
                        v[dh * 4 + dw] = plane[h + dh][w + dw];
                #pragma unroll
                for (int dh = 0; dh < 4; ++dh)
                    #pragma unroll
                    for (int dw = 0; dw < 4; ++dw) {
                        bool ok = (h + dh < h1) && (w + dw < w1);
                        m = fmaxf(m, ok ? v[dh * 4 + dw] : -FLT_MAX);
                    }
            }
        }

        out[((size_t)(r * NC + c)) * (NS * NS) + bin] = m;
    }
}

extern "C" void kernel_launch(void* const* d_in, const int* in_sizes, int n_in,
                              void* d_out, int out_size, void* d_ws, size_t ws_size,
                              hipStream_t stream)
{
    const float* feature_map = (const float*)d_in[0];
    const int*   rois        = (const int*)d_in[1];
    float*       out         = (float*)d_out;

    const int grid  = NC * (NR / RG);  // 256 * 8 = 2048 blocks
    const int block = 256;

    roi_pool_kernel<<<grid, block, 0, stream>>>(feature_map, rois, out);
}